// Round 1
// 365.880 us; speedup vs baseline: 1.0112x; 1.0112x over previous
//
#include <hip/hip_runtime.h>
#include <math.h>

#define Bsz   256
#define Nn    2048
#define Md    64
#define CSd   512
#define INPd  256
#define OUTd  256
#define KTOT  832      // INP + M + CS
#define PSTRIDE 272    // per-batch param block (floats)
#define GSZ   524288   // 256*2048 gates elements (one split partial)
#define ZSPL  4        // K splits for gates GEMM
#define KZ    208      // K per split = 832/4 = 13*16

__device__ __forceinline__ float sigmoidf_(float x){ return 1.f/(1.f+expf(-x)); }
__device__ __forceinline__ float softplusf_(float x){ return fmaxf(x,0.f) + log1pf(expf(-fabsf(x))); }

__device__ __forceinline__ float4 loadA4(const float* __restrict__ x, const float* __restrict__ pr,
                                         const float* __restrict__ h, int row, int k){
  if (k < INPd)            return *(const float4*)&x[row*INPd + k];
  else if (k < INPd+Md)    return *(const float4*)&pr[row*Md + (k-INPd)];
  else                     return *(const float4*)&h[row*CSd + (k-INPd-Md)];
}
__device__ __forceinline__ float4 loadW4(const float* __restrict__ Wih, const float* __restrict__ Whh,
                                         int j, int k){
  if (k < INPd+Md)         return *(const float4*)&Wih[j*(INPd+Md) + k];
  else                     return *(const float4*)&Whh[j*CSd + (k-INPd-Md)];
}

// ---------------- Kernel 1: gates partials, split-K GEMM
// [256x832] @ [832x2048]^T, tile 64x64, BK=16, Z=4, 256 thr/blk, 4x4/thread
// Staging: thread t loads row (t>>2), k-chunk (t&3)*4 -> 4 lanes cover one
// row's 64B = one full cache line (100% line utilization, 16 lines/wave).
__global__ __launch_bounds__(256) void k_gates(
    const float* __restrict__ x, const float* __restrict__ prev_read, const float* __restrict__ h,
    const float* __restrict__ W_ih, const float* __restrict__ W_hh,
    float* __restrict__ partials)
{
  __shared__ __align__(16) float As[16][68];   // [k][row], stride 272B
  __shared__ __align__(16) float Bs[16][68];   // [k][col]
  const int t = threadIdx.x;             // 0..255
  const int col0 = blockIdx.x * 64;
  const int row0 = blockIdx.y * 64;
  const int z    = blockIdx.z;
  const int lr = t >> 2;                 // 0..63 staging row/col
  const int kq = (t & 3) * 4;            // k offset within 16-slab
  const int tr = t >> 4, tc = t & 15;    // 16x16 compute grid
  const int arow = row0 + lr;
  const int bcol = col0 + lr;

  float acc[4][4] = {};
  int kb = z * KZ;
  float4 a  = loadA4(x, prev_read, h, arow, kb + kq);
  float4 bq = loadW4(W_ih, W_hh, bcol, kb + kq);

  for (int kc = 0; kc < 13; ++kc) {
    // commit staged regs to LDS (transposed [k][row])
    As[kq+0][lr] = a.x;  As[kq+1][lr] = a.y;  As[kq+2][lr] = a.z;  As[kq+3][lr] = a.w;
    Bs[kq+0][lr] = bq.x; Bs[kq+1][lr] = bq.y; Bs[kq+2][lr] = bq.z; Bs[kq+3][lr] = bq.w;
    __syncthreads();
    // prefetch next slab while computing
    if (kc < 12) {
      int kn = kb + (kc+1)*16 + kq;
      a  = loadA4(x, prev_read, h, arow, kn);
      bq = loadW4(W_ih, W_hh, bcol, kn);
    }
    #pragma unroll
    for (int kk = 0; kk < 16; ++kk) {
      float av[4], bv[4];
      *(float4*)&av[0] = *(const float4*)&As[kk][tr*4];
      *(float4*)&bv[0] = *(const float4*)&Bs[kk][tc*4];
      #pragma unroll
      for (int i=0;i<4;++i)
        #pragma unroll
        for (int q=0;q<4;++q)
          acc[i][q] += av[i]*bv[q];
    }
    __syncthreads();
  }
  float* part = partials + (size_t)z * GSZ;
  #pragma unroll
  for (int i=0;i<4;++i) {
    int r = row0 + tr*4 + i;
    float4 v0 = {acc[i][0],acc[i][1],acc[i][2],acc[i][3]};
    *(float4*)&part[r*2048 + col0 + tc*4] = v0;
  }
}

// ---------------- Kernel 2: fused LSTM elementwise + head projections + params
__global__ __launch_bounds__(512) void k_lstm_heads(
    const float* __restrict__ partials, const float* __restrict__ c,
    const float* __restrict__ b_ih, const float* __restrict__ b_hh,
    const float* __restrict__ W_r, const float* __restrict__ b_r,
    const float* __restrict__ W_w, const float* __restrict__ b_w,
    float* __restrict__ h_new, float* __restrict__ c_new, float* __restrict__ params)
{
  __shared__ float hs[CSd];
  __shared__ float ob[268];
  int b = blockIdx.x, t = threadIdx.x;
  // --- LSTM: thread t owns element (b, t)
  float g[4];
  #pragma unroll
  for (int q = 0; q < 4; ++q) {
    int col = q*512 + t;
    float s = b_ih[col] + b_hh[col];
    #pragma unroll
    for (int sp = 0; sp < ZSPL; ++sp) s += partials[(size_t)sp*GSZ + b*2048 + col];
    g[q] = s;
  }
  float ig = sigmoidf_(g[0]);
  float fg = sigmoidf_(g[1]);
  float gg = tanhf(g[2]);
  float og = sigmoidf_(g[3]);
  float cn = fg * c[b*CSd + t] + ig * gg;
  float hn = og * tanhf(cn);
  c_new[b*CSd + t] = cn;
  h_new[b*CSd + t] = hn;
  hs[t] = hn;
  __syncthreads();
  // --- heads: wave-per-row coalesced GEMV
  int wave = t >> 6, lane = t & 63;
  for (int r = wave; r < 268; r += 8) {
    const float* wrow; float bias;
    if (r < 70) { wrow = W_r + r*CSd;      bias = b_r[r]; }
    else        { wrow = W_w + (r-70)*CSd; bias = b_w[r-70]; }
    float s = 0.f;
    #pragma unroll
    for (int i = 0; i < 8; ++i) s += wrow[i*64 + lane] * hs[i*64 + lane];
    #pragma unroll
    for (int off = 32; off; off >>= 1) s += __shfl_xor(s, off);
    if (lane == 0) ob[r] = s + bias;
  }
  __syncthreads();
  float* P = params + b*PSTRIDE;
  if (t < 256) {
    if (t < 64)       P[t] = ob[t];                           // k_r
    else if (t < 128) P[t] = ob[70 + (t-64)];                 // k_w
    else if (t < 192) P[t] = sigmoidf_(ob[140 + (t-128)]);    // erase
    else              P[t] = ob[204 + (t-192)];               // add
  }
  float* S = P + 256;
  if (wave == 0) {
    float v = ob[lane]; float sq = v*v;
    #pragma unroll
    for (int off = 32; off; off >>= 1) sq += __shfl_xor(sq, off);
    if (lane == 0) S[6] = 1.f/(sqrtf(sq)+1e-8f);
  } else if (wave == 1) {
    float v = ob[70 + lane]; float sq = v*v;
    #pragma unroll
    for (int off = 32; off; off >>= 1) sq += __shfl_xor(sq, off);
    if (lane == 0) S[13] = 1.f/(sqrtf(sq)+1e-8f);
  }
  if (t == 128) {
    S[0] = softplusf_(ob[64]);
    S[1] = sigmoidf_(ob[65]);
    float m3 = fmaxf(ob[66], fmaxf(ob[67], ob[68]));
    float e0=expf(ob[66]-m3), e1=expf(ob[67]-m3), e2=expf(ob[68]-m3);
    float es = e0+e1+e2;
    S[2]=e0/es; S[3]=e1/es; S[4]=e2/es;
    S[5] = 1.f + softplusf_(ob[69]);
  }
  if (t == 129) {
    S[7] = softplusf_(ob[134]);
    S[8] = sigmoidf_(ob[135]);
    float m3 = fmaxf(ob[136], fmaxf(ob[137], ob[138]));
    float e0=expf(ob[136]-m3), e1=expf(ob[137]-m3), e2=expf(ob[138]-m3);
    float es = e0+e1+e2;
    S[9]=e0/es; S[10]=e1/es; S[11]=e2/es;
    S[12] = 1.f + softplusf_(ob[139]);
  }
}

// ---------------- Kernel 3: pass A over memory — beta*cosine-sim for both heads
// 64 rows per block; params loaded once per block.
__global__ __launch_bounds__(256) void k_sim(
    const float* __restrict__ mem, const float* __restrict__ params,
    float* __restrict__ a_r, float* __restrict__ a_w)
{
  int b = blockIdx.y;
  int n0 = blockIdx.x * 64;
  int rr = threadIdx.x >> 4;
  int chunk = threadIdx.x & 15;
  const float* P = params + b*PSTRIDE;
  float4 kr = ((const float4*)P)[chunk];
  float4 kw = ((const float4*)(P+64))[chunk];
  const float* S = P + 256;
  float cr = S[0] * S[6];
  float cw = S[7] * S[13];
  #pragma unroll
  for (int p = 0; p < 4; ++p) {
    int n = n0 + p*16 + rr;
    float4 v = ((const float4*)mem)[(b*Nn + n)*16 + chunk];
    float ss = v.x*v.x + v.y*v.y + v.z*v.z + v.w*v.w;
    float pr = v.x*kr.x + v.y*kr.y + v.z*kr.z + v.w*kr.w;
    float pw = v.x*kw.x + v.y*kw.y + v.z*kw.z + v.w*kw.w;
    #pragma unroll
    for (int off=8; off; off>>=1) {
      ss += __shfl_xor(ss, off);
      pr += __shfl_xor(pr, off);
      pw += __shfl_xor(pw, off);
    }
    if (chunk == 0) {
      float inv_nm = 1.f/(sqrtf(ss)+1e-8f);
      a_r[b*Nn+n] = cr * pr * inv_nm;
      a_w[b*Nn+n] = cw * pw * inv_nm;
    }
  }
}

// ---------------- Kernel 4: softmax -> interpolate -> shift -> sharpen -> normalize
__device__ __forceinline__ float block_reduce512(float val, float* red, int t, bool ismax){
  #pragma unroll
  for (int off=32; off; off>>=1)
    val = ismax ? fmaxf(val, __shfl_xor(val,off)) : val + __shfl_xor(val,off);
  __syncthreads();
  if ((t&63)==0) red[t>>6] = val;
  __syncthreads();
  float r = red[0];
  if (ismax) { for (int i=1;i<8;++i) r = fmaxf(r, red[i]); }
  else       { for (int i=1;i<8;++i) r += red[i]; }
  return r;
}

__global__ __launch_bounds__(512) void k_weights(
    const float* __restrict__ a_r, const float* __restrict__ a_w,
    const float* __restrict__ read_w, const float* __restrict__ write_w,
    const float* __restrict__ params,
    float* __restrict__ w_read, float* __restrict__ w_write)
{
  __shared__ float wg[Nn];
  __shared__ float red[8];
  int b = blockIdx.x;
  int which = blockIdx.y;
  const float* a    = which ? a_w     : a_r;
  const float* prev = which ? write_w : read_w;
  float* outw       = which ? w_write : w_read;
  const float* S = params + b*PSTRIDE + 256 + (which ? 7 : 0);
  float g = S[1], s0 = S[2], s1 = S[3], s2 = S[4], gamma = S[5];
  int t = threadIdx.x;
  float v[4];
  #pragma unroll
  for (int i=0;i<4;++i) v[i] = a[b*Nn + t*4+i];
  float lmax = fmaxf(fmaxf(v[0],v[1]), fmaxf(v[2],v[3]));
  float mx = block_reduce512(lmax, red, t, true);
  float e[4]; float ps = 0.f;
  #pragma unroll
  for (int i=0;i<4;++i){ e[i] = expf(v[i]-mx); ps += e[i]; }
  float denom = block_reduce512(ps, red, t, false);
  float inv = 1.f/denom;
  #pragma unroll
  for (int i=0;i<4;++i){
    float wc = e[i]*inv;
    wg[t*4+i] = g*wc + (1.f-g)*prev[b*Nn + t*4+i];
  }
  __syncthreads();
  float wp[4]; float psum = 0.f;
  #pragma unroll
  for (int i=0;i<4;++i){
    int n = t*4+i;
    float wsv = s0*wg[(n+Nn-1)&(Nn-1)] + s1*wg[n] + s2*wg[(n+1)&(Nn-1)];
    wp[i] = powf(wsv, gamma);
    psum += wp[i];
  }
  float tot = block_reduce512(psum, red, t, false);
  float invt = 1.f/(tot + 1e-8f);
  #pragma unroll
  for (int i=0;i<4;++i) outw[b*Nn + t*4+i] = wp[i]*invt;
}

// ---------------- Kernel 5: pass B — memory_new + read_vec block partials
__global__ __launch_bounds__(256) void k_memupd(
    const float* __restrict__ mem, const float* __restrict__ params,
    const float* __restrict__ w_read, const float* __restrict__ w_write,
    float* __restrict__ mem_new, float* __restrict__ prv)
{
  __shared__ __align__(16) float er[64];
  __shared__ __align__(16) float ad[64];
  __shared__ float4 part[64];
  int b = blockIdx.y;
  int n0 = blockIdx.x * 64;
  int t = threadIdx.x;
  const float* P = params + b*PSTRIDE;
  if (t < 64)       er[t]    = P[128+t];
  else if (t < 128) ad[t-64] = P[192+(t-64)];
  __syncthreads();
  int chunk = t & 15;
  int rr = t >> 4;
  float4 e4 = ((const float4*)er)[chunk];
  float4 a4 = ((const float4*)ad)[chunk];
  float4 acc = {0.f,0.f,0.f,0.f};
  #pragma unroll
  for (int p = 0; p < 4; ++p) {
    int n = n0 + p*16 + rr;
    float4 v = ((const float4*)mem)[(b*Nn+n)*16 + chunk];
    float ww = w_write[b*Nn+n];
    float wr = w_read[b*Nn+n];
    float4 o;
    o.x = v.x*(1.f-ww*e4.x) + ww*a4.x;
    o.y = v.y*(1.f-ww*e4.y) + ww*a4.y;
    o.z = v.z*(1.f-ww*e4.z) + ww*a4.z;
    o.w = v.w*(1.f-ww*e4.w) + ww*a4.w;
    ((float4*)mem_new)[(b*Nn+n)*16 + chunk] = o;
    acc.x += wr*v.x; acc.y += wr*v.y; acc.z += wr*v.z; acc.w += wr*v.w;
  }
  #pragma unroll
  for (int off = 16; off <= 32; off <<= 1) {
    acc.x += __shfl_xor(acc.x, off);
    acc.y += __shfl_xor(acc.y, off);
    acc.z += __shfl_xor(acc.z, off);
    acc.w += __shfl_xor(acc.w, off);
  }
  int wave = t >> 6;
  if ((t & 63) < 16) part[wave*16 + chunk] = acc;
  __syncthreads();
  if (t < 16) {
    float4 s = part[t];
    for (int w=1; w<4; ++w){ float4 q = part[w*16+t]; s.x+=q.x; s.y+=q.y; s.z+=q.z; s.w+=q.w; }
    *(float4*)&prv[(b*32 + blockIdx.x)*64 + t*4] = s;
  }
}

// ---------------- Kernel 6: reduce read_vec + out GEMV
__global__ __launch_bounds__(256) void k_out(
    const float* __restrict__ h_new, const float* __restrict__ prv,
    const float* __restrict__ W_o, const float* __restrict__ b_o,
    float* __restrict__ out, float* __restrict__ read_vec)
{
  __shared__ float vbuf[576];
  int b = blockIdx.y, t = threadIdx.x;
  vbuf[t]     = h_new[b*CSd + t];
  vbuf[t+256] = h_new[b*CSd + t + 256];
  if (t < 64) {
    float s = 0.f;
    #pragma unroll 8
    for (int i = 0; i < 32; ++i) s += prv[(b*32 + i)*64 + t];
    vbuf[512+t] = s;
    if (blockIdx.x == 0) read_vec[b*64 + t] = s;
  }
  __syncthreads();
  int wave = t >> 6, lane = t & 63;
  float vb[9];
  #pragma unroll
  for (int i = 0; i < 9; ++i) vb[i] = vbuf[i*64 + lane];
  int cbase = blockIdx.x*64 + wave*16;
  for (int jj = 0; jj < 16; ++jj) {
    int cc = cbase + jj;
    const float* w = W_o + cc*576;
    float s = 0.f;
    #pragma unroll
    for (int i = 0; i < 9; ++i) s += w[i*64 + lane] * vb[i];
    #pragma unroll
    for (int off = 32; off; off >>= 1) s += __shfl_xor(s, off);
    if (lane == 0) out[b*OUTd + cc] = s + b_o[cc];
  }
}

extern "C" void kernel_launch(void* const* d_in, const int* in_sizes, int n_in,
                              void* d_out, int out_size, void* d_ws, size_t ws_size,
                              hipStream_t stream)
{
  const float* x         = (const float*)d_in[0];
  const float* memory    = (const float*)d_in[1];
  const float* h         = (const float*)d_in[2];
  const float* c         = (const float*)d_in[3];
  const float* read_w    = (const float*)d_in[4];
  const float* write_w   = (const float*)d_in[5];
  const float* prev_read = (const float*)d_in[6];
  const float* W_ih      = (const float*)d_in[7];
  const float* W_hh      = (const float*)d_in[8];
  const float* b_ih      = (const float*)d_in[9];
  const float* b_hh      = (const float*)d_in[10];
  const float* W_r       = (const float*)d_in[11];
  const float* b_r       = (const float*)d_in[12];
  const float* W_w       = (const float*)d_in[13];
  const float* b_w       = (const float*)d_in[14];
  const float* W_o       = (const float*)d_in[15];
  const float* b_o       = (const float*)d_in[16];

  float* out      = (float*)d_out;
  float* mem_new  = out + 256*256;
  float* h_new    = mem_new + (size_t)256*2048*64;
  float* c_new    = h_new + 256*512;
  float* w_read   = c_new + 256*512;
  float* w_write  = w_read + 256*2048;
  float* read_vec = w_write + 256*2048;

  float* ws       = (float*)d_ws;
  float* params   = ws;                      // 256*PSTRIDE floats
  float* partials = params + 256*PSTRIDE;    // ZSPL * GSZ floats (8 MB)
  // aliases into dead partials space (sequential stream ordering makes this safe):
  float* a_r      = partials;                // live k_sim -> k_weights
  float* a_w      = partials + GSZ;
  float* prv      = partials + 2*GSZ;        // live k_memupd -> k_out (256*32*64)

  k_gates     <<<dim3(32,4,ZSPL), 256, 0, stream>>>(x, prev_read, h, W_ih, W_hh, partials);
  k_lstm_heads<<<256,            512, 0, stream>>>(partials, c, b_ih, b_hh, W_r, b_r, W_w, b_w,
                                                   h_new, c_new, params);
  k_sim       <<<dim3(32,256),   256, 0, stream>>>(memory, params, a_r, a_w);
  k_weights   <<<dim3(256,2),    512, 0, stream>>>(a_r, a_w, read_w, write_w, params, w_read, w_write);
  k_memupd    <<<dim3(32,256),   256, 0, stream>>>(memory, params, w_read, w_write, mem_new, prv);
  k_out       <<<dim3(4,256),    256, 0, stream>>>(h_new, prv, W_o, b_o, out, read_vec);
}

// Round 4
// 358.800 us; speedup vs baseline: 1.0312x; 1.0197x over previous
//
#include <hip/hip_runtime.h>
#include <math.h>

#define Bsz   256
#define Nn    2048
#define Md    64
#define CSd   512
#define INPd  256
#define OUTd  256
#define KTOT  832      // INP + M + CS
#define PSTRIDE 128    // per-batch param block: erase[64] + add[64]
#define GSZ   524288   // 256*2048 gates elements (one split partial)
#define ZSPL  2        // K splits for gates GEMM
#define KZ    416      // K per split = 832/2 = 26*16

__device__ __forceinline__ float sigmoidf_(float x){ return 1.f/(1.f+expf(-x)); }
__device__ __forceinline__ float softplusf_(float x){ return fmaxf(x,0.f) + log1pf(expf(-fabsf(x))); }

__device__ __forceinline__ float4 loadA4(const float* __restrict__ x, const float* __restrict__ pr,
                                         const float* __restrict__ h, int row, int k){
  if (k < INPd)            return *(const float4*)&x[row*INPd + k];
  else if (k < INPd+Md)    return *(const float4*)&pr[row*Md + (k-INPd)];
  else                     return *(const float4*)&h[row*CSd + (k-INPd-Md)];
}
__device__ __forceinline__ float4 loadW4(const float* __restrict__ Wih, const float* __restrict__ Whh,
                                         int j, int k){
  if (k < INPd+Md)         return *(const float4*)&Wih[j*(INPd+Md) + k];
  else                     return *(const float4*)&Whh[j*CSd + (k-INPd-Md)];
}

// ---------------- Kernel 1: gates partials, split-K GEMM
// [256x832] @ [832x2048]^T, tile 64x64, BK=16, Z=2, 256 thr/blk, 4x4/thread
__global__ __launch_bounds__(256) void k_gates(
    const float* __restrict__ x, const float* __restrict__ prev_read, const float* __restrict__ h,
    const float* __restrict__ W_ih, const float* __restrict__ W_hh,
    float* __restrict__ partials)
{
  __shared__ __align__(16) float As[16][68];   // [k][row]
  __shared__ __align__(16) float Bs[16][68];   // [k][col]
  const int t = threadIdx.x;             // 0..255
  const int col0 = blockIdx.x * 64;
  const int row0 = blockIdx.y * 64;
  const int z    = blockIdx.z;
  const int lr = t >> 2;                 // 0..63 staging row/col
  const int kq = (t & 3) * 4;            // k offset within 16-slab
  const int tr = t >> 4, tc = t & 15;    // 16x16 compute grid
  const int arow = row0 + lr;
  const int bcol = col0 + lr;

  float acc[4][4] = {};
  int kb = z * KZ;
  float4 a  = loadA4(x, prev_read, h, arow, kb + kq);
  float4 bq = loadW4(W_ih, W_hh, bcol, kb + kq);

  for (int kc = 0; kc < 26; ++kc) {
    As[kq+0][lr] = a.x;  As[kq+1][lr] = a.y;  As[kq+2][lr] = a.z;  As[kq+3][lr] = a.w;
    Bs[kq+0][lr] = bq.x; Bs[kq+1][lr] = bq.y; Bs[kq+2][lr] = bq.z; Bs[kq+3][lr] = bq.w;
    __syncthreads();
    if (kc < 25) {
      int kn = kb + (kc+1)*16 + kq;
      a  = loadA4(x, prev_read, h, arow, kn);
      bq = loadW4(W_ih, W_hh, bcol, kn);
    }
    #pragma unroll
    for (int kk = 0; kk < 16; ++kk) {
      float av[4], bv[4];
      *(float4*)&av[0] = *(const float4*)&As[kk][tr*4];
      *(float4*)&bv[0] = *(const float4*)&Bs[kk][tc*4];
      #pragma unroll
      for (int i=0;i<4;++i)
        #pragma unroll
        for (int q=0;q<4;++q)
          acc[i][q] += av[i]*bv[q];
    }
    __syncthreads();
  }
  float* part = partials + (size_t)z * GSZ;
  #pragma unroll
  for (int i=0;i<4;++i) {
    int r = row0 + tr*4 + i;
    float4 v0 = {acc[i][0],acc[i][1],acc[i][2],acc[i][3]};
    *(float4*)&part[r*2048 + col0 + tc*4] = v0;
  }
}

// ---------------- Kernel 2: per-batch fused LSTM + heads + sim + addressing
// one block per batch, 1024 threads (16 waves)
__device__ __forceinline__ float hreduce(float val, float* red, int t, bool ismax){
  #pragma unroll
  for (int off=32; off; off>>=1)
    val = ismax ? fmaxf(val, __shfl_xor(val,off)) : val + __shfl_xor(val,off);
  __syncthreads();
  if ((t&63)==0) red[t>>6] = val;
  __syncthreads();
  int base = (t>>9)*8;            // per-half reduction (waves 0-7 / 8-15)
  float r = red[base];
  if (ismax) { for (int i=1;i<8;++i) r = fmaxf(r, red[base+i]); }
  else       { for (int i=1;i<8;++i) r += red[base+i]; }
  return r;
}

__global__ __launch_bounds__(1024) void k_fused(
    const float* __restrict__ partials, const float* __restrict__ c,
    const float* __restrict__ b_ih, const float* __restrict__ b_hh,
    const float* __restrict__ W_r, const float* __restrict__ b_r,
    const float* __restrict__ W_w, const float* __restrict__ b_w,
    const float* __restrict__ mem,
    const float* __restrict__ read_w, const float* __restrict__ write_w,
    float* __restrict__ h_new, float* __restrict__ c_new,
    float* __restrict__ w_read, float* __restrict__ w_write,
    float* __restrict__ params)
{
  __shared__ __align__(16) float hs[CSd];
  __shared__ float ob[268];
  __shared__ __align__(16) float sim[2][Nn];   // 16 KB; reused as wg
  __shared__ float red[16];
  __shared__ float sc[16];
  __shared__ __align__(16) float kvec[128];
  int b = blockIdx.x, t = threadIdx.x;

  // --- P0: LSTM elementwise (threads 0..511)
  if (t < CSd) {
    float g[4];
    #pragma unroll
    for (int q = 0; q < 4; ++q) {
      int col = q*512 + t;
      float s = b_ih[col] + b_hh[col];
      #pragma unroll
      for (int sp = 0; sp < ZSPL; ++sp) s += partials[(size_t)sp*GSZ + b*2048 + col];
      g[q] = s;
    }
    float ig = sigmoidf_(g[0]);
    float fg = sigmoidf_(g[1]);
    float gg = tanhf(g[2]);
    float og = sigmoidf_(g[3]);
    float cn = fg * c[b*CSd + t] + ig * gg;
    float hn = og * tanhf(cn);
    c_new[b*CSd + t] = cn;
    h_new[b*CSd + t] = hn;
    hs[t] = hn;
  }
  __syncthreads();

  // --- P1: heads GEMV, wave-per-row (16 waves)
  int wave = t >> 6, lane = t & 63;
  for (int r = wave; r < 268; r += 16) {
    const float* wrow; float bias;
    if (r < 70) { wrow = W_r + r*CSd;      bias = b_r[r]; }
    else        { wrow = W_w + (r-70)*CSd; bias = b_w[r-70]; }
    float s = 0.f;
    #pragma unroll
    for (int i = 0; i < 8; ++i) s += wrow[i*64 + lane] * hs[i*64 + lane];
    #pragma unroll
    for (int off = 32; off; off >>= 1) s += __shfl_xor(s, off);
    if (lane == 0) ob[r] = s + bias;
  }
  __syncthreads();

  // --- P2: params (scalars to sc[], keys to kvec[], erase/add to global)
  if (wave == 0) {
    float v = ob[lane]; float sq = v*v;
    #pragma unroll
    for (int off = 32; off; off >>= 1) sq += __shfl_xor(sq, off);
    if (lane == 0) sc[6] = 1.f/(sqrtf(sq)+1e-8f);
  } else if (wave == 1) {
    float v = ob[70 + lane]; float sq = v*v;
    #pragma unroll
    for (int off = 32; off; off >>= 1) sq += __shfl_xor(sq, off);
    if (lane == 0) sc[13] = 1.f/(sqrtf(sq)+1e-8f);
  }
  if (t == 128) {
    sc[0] = softplusf_(ob[64]);
    sc[1] = sigmoidf_(ob[65]);
    float m3 = fmaxf(ob[66], fmaxf(ob[67], ob[68]));
    float e0=expf(ob[66]-m3), e1=expf(ob[67]-m3), e2=expf(ob[68]-m3);
    float es = e0+e1+e2;
    sc[2]=e0/es; sc[3]=e1/es; sc[4]=e2/es;
    sc[5] = 1.f + softplusf_(ob[69]);
  }
  if (t == 129) {
    sc[7] = softplusf_(ob[134]);
    sc[8] = sigmoidf_(ob[135]);
    float m3 = fmaxf(ob[136], fmaxf(ob[137], ob[138]));
    float e0=expf(ob[136]-m3), e1=expf(ob[137]-m3), e2=expf(ob[138]-m3);
    float es = e0+e1+e2;
    sc[9]=e0/es; sc[10]=e1/es; sc[11]=e2/es;
    sc[12] = 1.f + softplusf_(ob[139]);
  }
  if (t >= 256 && t < 384) {
    int i = t - 256;
    kvec[i] = (i < 64) ? ob[i] : ob[70 + (i-64)];
  }
  if (t >= 384 && t < 512) {
    int i = t - 384;
    params[b*PSTRIDE + i] = (i < 64) ? sigmoidf_(ob[140+i]) : ob[204 + (i-64)];
  }
  __syncthreads();

  // --- P3: cosine sim over all 2048 rows (16 lanes per row, 64 rows/pass)
  {
    int rr = t >> 4, chunk = t & 15;
    float4 kr = ((const float4*)kvec)[chunk];
    float4 kw = ((const float4*)(kvec+64))[chunk];
    float cr = sc[0]*sc[6];
    float cw = sc[7]*sc[13];
    #pragma unroll 4
    for (int p = 0; p < 32; ++p) {
      int n = p*64 + rr;
      float4 v = ((const float4*)mem)[((size_t)b*Nn + n)*16 + chunk];
      float ss = v.x*v.x + v.y*v.y + v.z*v.z + v.w*v.w;
      float pr = v.x*kr.x + v.y*kr.y + v.z*kr.z + v.w*kr.w;
      float pw = v.x*kw.x + v.y*kw.y + v.z*kw.z + v.w*kw.w;
      #pragma unroll
      for (int off=8; off; off>>=1) {
        ss += __shfl_xor(ss, off);
        pr += __shfl_xor(pr, off);
        pw += __shfl_xor(pw, off);
      }
      if (chunk == 0) {
        float inv_nm = 1.f/(sqrtf(ss)+1e-8f);
        sim[0][n] = cr * pr * inv_nm;
        sim[1][n] = cw * pw * inv_nm;
      }
    }
  }
  __syncthreads();

  // --- P4: dual softmax/interp/shift/sharpen (half-block per head)
  {
    int which = t >> 9;          // 0 = read head, 1 = write head
    int tt = t & 511;
    const float* prev = which ? (write_w + b*Nn) : (read_w + b*Nn);
    float* outw       = which ? (w_write + b*Nn) : (w_read + b*Nn);
    const float* S = sc + which*7;
    float g = S[1], s0 = S[2], s1 = S[3], s2 = S[4], gamma = S[5];
    float4 v4 = *(const float4*)&sim[which][tt*4];
    float v[4] = {v4.x, v4.y, v4.z, v4.w};
    float lmax = fmaxf(fmaxf(v[0],v[1]), fmaxf(v[2],v[3]));
    float mx = hreduce(lmax, red, t, true);
    float e[4]; float ps = 0.f;
    #pragma unroll
    for (int i=0;i<4;++i){ e[i] = expf(v[i]-mx); ps += e[i]; }
    float denom = hreduce(ps, red, t, false);
    float inv = 1.f/denom;
    float4 p4 = ((const float4*)prev)[tt];
    float pv[4] = {p4.x, p4.y, p4.z, p4.w};
    float* wg = sim[which];
    #pragma unroll
    for (int i=0;i<4;++i){
      float wc = e[i]*inv;
      wg[tt*4+i] = g*wc + (1.f-g)*pv[i];
    }
    __syncthreads();
    float wp[4]; float psum = 0.f;
    #pragma unroll
    for (int i=0;i<4;++i){
      int n = tt*4+i;
      float wsv = s0*wg[(n+Nn-1)&(Nn-1)] + s1*wg[n] + s2*wg[(n+1)&(Nn-1)];
      wp[i] = powf(wsv, gamma);
      psum += wp[i];
    }
    float tot = hreduce(psum, red, t, false);
    float invt = 1.f/(tot + 1e-8f);
    float4 o4 = {wp[0]*invt, wp[1]*invt, wp[2]*invt, wp[3]*invt};
    ((float4*)outw)[tt] = o4;
  }
}

// ---------------- Kernel 3: per-batch memory update + read_vec + out GEMV
__global__ __launch_bounds__(1024) void k_mo(
    const float* __restrict__ mem, const float* __restrict__ params,
    const float* __restrict__ w_read, const float* __restrict__ w_write,
    const float* __restrict__ h_new,
    const float* __restrict__ W_o, const float* __restrict__ b_o,
    float* __restrict__ mem_new, float* __restrict__ read_vec, float* __restrict__ out)
{
  __shared__ __align__(16) float er[64];
  __shared__ __align__(16) float ad[64];
  __shared__ __align__(16) float4 part[16][16];   // [wave][chunk]
  __shared__ __align__(16) float vbuf[576];
  int b = blockIdx.x, t = threadIdx.x;
  const float* P = params + b*PSTRIDE;
  if (t < 64)       er[t]    = P[t];
  else if (t < 128) ad[t-64] = P[64+(t-64)];
  if (t < CSd) vbuf[t] = h_new[b*CSd + t];
  __syncthreads();

  // --- P1: stream memory rows (64 rows in flight, 32 passes)
  int chunk = t & 15;
  int rr = t >> 4;                 // 0..63
  int wave = t >> 6, lane = t & 63;
  float4 e4 = ((const float4*)er)[chunk];
  float4 a4 = ((const float4*)ad)[chunk];
  float4 acc = {0.f,0.f,0.f,0.f};
  #pragma unroll 4
  for (int p = 0; p < 32; ++p) {
    int n = p*64 + rr;
    float4 v = ((const float4*)mem)[((size_t)b*Nn+n)*16 + chunk];
    float ww = w_write[b*Nn+n];
    float wr = w_read[b*Nn+n];
    float4 o;
    o.x = v.x*(1.f-ww*e4.x) + ww*a4.x;
    o.y = v.y*(1.f-ww*e4.y) + ww*a4.y;
    o.z = v.z*(1.f-ww*e4.z) + ww*a4.z;
    o.w = v.w*(1.f-ww*e4.w) + ww*a4.w;
    ((float4*)mem_new)[((size_t)b*Nn+n)*16 + chunk] = o;
    acc.x += wr*v.x; acc.y += wr*v.y; acc.z += wr*v.z; acc.w += wr*v.w;
  }
  #pragma unroll
  for (int off = 16; off <= 32; off <<= 1) {
    acc.x += __shfl_xor(acc.x, off);
    acc.y += __shfl_xor(acc.y, off);
    acc.z += __shfl_xor(acc.z, off);
    acc.w += __shfl_xor(acc.w, off);
  }
  if (lane < 16) part[wave][chunk] = acc;
  __syncthreads();

  // --- P2: finish read_vec reduction
  if (t < 16) {
    float4 s = part[0][t];
    #pragma unroll
    for (int w=1; w<16; ++w){ float4 q = part[w][t]; s.x+=q.x; s.y+=q.y; s.z+=q.z; s.w+=q.w; }
    *(float4*)&vbuf[512 + t*4] = s;
    *(float4*)&read_vec[b*64 + t*4] = s;
  }
  __syncthreads();

  // --- P3: out GEMV (16 waves x 16 cols)
  float vb[9];
  #pragma unroll
  for (int i = 0; i < 9; ++i) vb[i] = vbuf[i*64 + lane];
  for (int jj = 0; jj < 16; ++jj) {
    int cc = wave*16 + jj;
    const float* w = W_o + cc*576;
    float s = 0.f;
    #pragma unroll
    for (int i = 0; i < 9; ++i) s += w[i*64 + lane] * vb[i];
    #pragma unroll
    for (int off = 32; off; off >>= 1) s += __shfl_xor(s, off);
    if (lane == 0) out[b*OUTd + cc] = s + b_o[cc];
  }
}

extern "C" void kernel_launch(void* const* d_in, const int* in_sizes, int n_in,
                              void* d_out, int out_size, void* d_ws, size_t ws_size,
                              hipStream_t stream)
{
  const float* x         = (const float*)d_in[0];
  const float* memory    = (const float*)d_in[1];
  const float* h         = (const float*)d_in[2];
  const float* c         = (const float*)d_in[3];
  const float* read_w    = (const float*)d_in[4];
  const float* write_w   = (const float*)d_in[5];
  const float* prev_read = (const float*)d_in[6];
  const float* W_ih      = (const float*)d_in[7];
  const float* W_hh      = (const float*)d_in[8];
  const float* b_ih      = (const float*)d_in[9];
  const float* b_hh      = (const float*)d_in[10];
  const float* W_r       = (const float*)d_in[11];
  const float* b_r       = (const float*)d_in[12];
  const float* W_w       = (const float*)d_in[13];
  const float* b_w       = (const float*)d_in[14];
  const float* W_o       = (const float*)d_in[15];
  const float* b_o       = (const float*)d_in[16];

  float* out      = (float*)d_out;
  float* mem_new  = out + 256*256;
  float* h_new    = mem_new + (size_t)256*2048*64;
  float* c_new    = h_new + 256*512;
  float* w_read   = c_new + 256*512;
  float* w_write  = w_read + 256*2048;
  float* read_vec = w_write + 256*2048;

  float* ws       = (float*)d_ws;
  float* params   = ws;                      // 256*PSTRIDE floats
  float* partials = params + 256*PSTRIDE;    // ZSPL * GSZ floats (4 MB)

  k_gates<<<dim3(32,4,ZSPL), 256, 0, stream>>>(x, prev_read, h, W_ih, W_hh, partials);
  k_fused<<<256, 1024, 0, stream>>>(partials, c, b_ih, b_hh, W_r, b_r, W_w, b_w,
                                    memory, read_w, write_w,
                                    h_new, c_new, w_read, w_write, params);
  k_mo   <<<256, 1024, 0, stream>>>(memory, params, w_read, w_write, h_new,
                                    W_o, b_o, mem_new, read_vec, out);
}

// Round 5
// 358.171 us; speedup vs baseline: 1.0330x; 1.0018x over previous
//
#include <hip/hip_runtime.h>
#include <math.h>

#define Bsz   256
#define Nn    2048
#define Md    64
#define CSd   512
#define INPd  256
#define OUTd  256
#define KTOT  832      // INP + M + CS
#define PSTRIDE 128    // per-batch param block: erase[64] + add[64]
#define GSZ   524288   // 256*2048 gates elements (one split partial)
#define ZSPL  2        // K splits for gates GEMM
#define KZ    416      // K per split = 832/2 = 26*16

__device__ __forceinline__ float sigmoidf_(float x){ return 1.f/(1.f+expf(-x)); }
__device__ __forceinline__ float softplusf_(float x){ return fmaxf(x,0.f) + log1pf(expf(-fabsf(x))); }

__device__ __forceinline__ float4 loadA4(const float* __restrict__ x, const float* __restrict__ pr,
                                         const float* __restrict__ h, int row, int k){
  if (k < INPd)            return *(const float4*)&x[row*INPd + k];
  else if (k < INPd+Md)    return *(const float4*)&pr[row*Md + (k-INPd)];
  else                     return *(const float4*)&h[row*CSd + (k-INPd-Md)];
}
__device__ __forceinline__ float4 loadW4(const float* __restrict__ Wih, const float* __restrict__ Whh,
                                         int j, int k){
  if (k < INPd+Md)         return *(const float4*)&Wih[j*(INPd+Md) + k];
  else                     return *(const float4*)&Whh[j*CSd + (k-INPd-Md)];
}

// ---------------- Kernel 1: gates partials, split-K GEMM
// [256x832] @ [832x2048]^T, tile 64x64, BK=16, Z=2, 256 thr/blk, 4x4/thread
__global__ __launch_bounds__(256) void k_gates(
    const float* __restrict__ x, const float* __restrict__ prev_read, const float* __restrict__ h,
    const float* __restrict__ W_ih, const float* __restrict__ W_hh,
    float* __restrict__ partials)
{
  __shared__ __align__(16) float As[16][68];   // [k][row]
  __shared__ __align__(16) float Bs[16][68];   // [k][col]
  const int t = threadIdx.x;             // 0..255
  const int col0 = blockIdx.x * 64;
  const int row0 = blockIdx.y * 64;
  const int z    = blockIdx.z;
  const int lr = t >> 2;                 // 0..63 staging row/col
  const int kq = (t & 3) * 4;            // k offset within 16-slab
  const int tr = t >> 4, tc = t & 15;    // 16x16 compute grid
  const int arow = row0 + lr;
  const int bcol = col0 + lr;

  float acc[4][4] = {};
  int kb = z * KZ;
  float4 a  = loadA4(x, prev_read, h, arow, kb + kq);
  float4 bq = loadW4(W_ih, W_hh, bcol, kb + kq);

  for (int kc = 0; kc < 26; ++kc) {
    As[kq+0][lr] = a.x;  As[kq+1][lr] = a.y;  As[kq+2][lr] = a.z;  As[kq+3][lr] = a.w;
    Bs[kq+0][lr] = bq.x; Bs[kq+1][lr] = bq.y; Bs[kq+2][lr] = bq.z; Bs[kq+3][lr] = bq.w;
    __syncthreads();
    if (kc < 25) {
      int kn = kb + (kc+1)*16 + kq;
      a  = loadA4(x, prev_read, h, arow, kn);
      bq = loadW4(W_ih, W_hh, bcol, kn);
    }
    #pragma unroll
    for (int kk = 0; kk < 16; ++kk) {
      float av[4], bv[4];
      *(float4*)&av[0] = *(const float4*)&As[kk][tr*4];
      *(float4*)&bv[0] = *(const float4*)&Bs[kk][tc*4];
      #pragma unroll
      for (int i=0;i<4;++i)
        #pragma unroll
        for (int q=0;q<4;++q)
          acc[i][q] += av[i]*bv[q];
    }
    __syncthreads();
  }
  float* part = partials + (size_t)z * GSZ;
  #pragma unroll
  for (int i=0;i<4;++i) {
    int r = row0 + tr*4 + i;
    float4 v0 = {acc[i][0],acc[i][1],acc[i][2],acc[i][3]};
    *(float4*)&part[r*2048 + col0 + tc*4] = v0;
  }
}

// ---------------- Kernel 2: per-batch fused LSTM + heads + sim + addressing
// one block per batch, 1024 threads (16 waves)
__device__ __forceinline__ float hreduce(float val, float* red, int t, bool ismax){
  #pragma unroll
  for (int off=32; off; off>>=1)
    val = ismax ? fmaxf(val, __shfl_xor(val,off)) : val + __shfl_xor(val,off);
  __syncthreads();
  if ((t&63)==0) red[t>>6] = val;
  __syncthreads();
  int base = (t>>9)*8;            // per-half reduction (waves 0-7 / 8-15)
  float r = red[base];
  if (ismax) { for (int i=1;i<8;++i) r = fmaxf(r, red[base+i]); }
  else       { for (int i=1;i<8;++i) r += red[base+i]; }
  return r;
}

__global__ __launch_bounds__(1024) void k_fused(
    const float* __restrict__ partials, const float* __restrict__ c,
    const float* __restrict__ b_ih, const float* __restrict__ b_hh,
    const float* __restrict__ W_r, const float* __restrict__ b_r,
    const float* __restrict__ W_w, const float* __restrict__ b_w,
    const float* __restrict__ mem,
    const float* __restrict__ read_w, const float* __restrict__ write_w,
    float* __restrict__ h_new, float* __restrict__ c_new,
    float* __restrict__ w_read, float* __restrict__ w_write,
    float* __restrict__ params)
{
  __shared__ __align__(16) float hs[CSd];
  __shared__ float ob[268];
  __shared__ __align__(16) float sim[2][Nn];   // 16 KB; reused as wg
  __shared__ float red[16];
  __shared__ float sc[16];
  __shared__ __align__(16) float kvec[128];
  int b = blockIdx.x, t = threadIdx.x;

  // Hoisted P4 inputs: issue the prev-weights load NOW; consumed after P3.
  int which = t >> 9;          // 0 = read head, 1 = write head
  int tt = t & 511;
  const float* prev = which ? (write_w + b*Nn) : (read_w + b*Nn);
  float* outw       = which ? (w_write + b*Nn) : (w_read + b*Nn);
  float4 p4 = ((const float4*)prev)[tt];

  // --- P0: LSTM elementwise (threads 0..511)
  if (t < CSd) {
    float g[4];
    #pragma unroll
    for (int q = 0; q < 4; ++q) {
      int col = q*512 + t;
      float s = b_ih[col] + b_hh[col];
      #pragma unroll
      for (int sp = 0; sp < ZSPL; ++sp) s += partials[(size_t)sp*GSZ + b*2048 + col];
      g[q] = s;
    }
    float ig = sigmoidf_(g[0]);
    float fg = sigmoidf_(g[1]);
    float gg = tanhf(g[2]);
    float og = sigmoidf_(g[3]);
    float cn = fg * c[b*CSd + t] + ig * gg;
    float hn = og * tanhf(cn);
    c_new[b*CSd + t] = cn;
    h_new[b*CSd + t] = hn;
    hs[t] = hn;
  }
  __syncthreads();

  // --- P1: heads GEMV, wave-per-row (16 waves)
  int wave = t >> 6, lane = t & 63;
  for (int r = wave; r < 268; r += 16) {
    const float* wrow; float bias;
    if (r < 70) { wrow = W_r + r*CSd;      bias = b_r[r]; }
    else        { wrow = W_w + (r-70)*CSd; bias = b_w[r-70]; }
    float s = 0.f;
    #pragma unroll
    for (int i = 0; i < 8; ++i) s += wrow[i*64 + lane] * hs[i*64 + lane];
    #pragma unroll
    for (int off = 32; off; off >>= 1) s += __shfl_xor(s, off);
    if (lane == 0) ob[r] = s + bias;
  }
  __syncthreads();

  // --- P2: params (scalars to sc[], keys to kvec[], erase/add to global)
  if (wave == 0) {
    float v = ob[lane]; float sq = v*v;
    #pragma unroll
    for (int off = 32; off; off >>= 1) sq += __shfl_xor(sq, off);
    if (lane == 0) sc[6] = 1.f/(sqrtf(sq)+1e-8f);
  } else if (wave == 1) {
    float v = ob[70 + lane]; float sq = v*v;
    #pragma unroll
    for (int off = 32; off; off >>= 1) sq += __shfl_xor(sq, off);
    if (lane == 0) sc[13] = 1.f/(sqrtf(sq)+1e-8f);
  }
  if (t == 128) {
    sc[0] = softplusf_(ob[64]);
    sc[1] = sigmoidf_(ob[65]);
    float m3 = fmaxf(ob[66], fmaxf(ob[67], ob[68]));
    float e0=expf(ob[66]-m3), e1=expf(ob[67]-m3), e2=expf(ob[68]-m3);
    float es = e0+e1+e2;
    sc[2]=e0/es; sc[3]=e1/es; sc[4]=e2/es;
    sc[5] = 1.f + softplusf_(ob[69]);
  }
  if (t == 129) {
    sc[7] = softplusf_(ob[134]);
    sc[8] = sigmoidf_(ob[135]);
    float m3 = fmaxf(ob[136], fmaxf(ob[137], ob[138]));
    float e0=expf(ob[136]-m3), e1=expf(ob[137]-m3), e2=expf(ob[138]-m3);
    float es = e0+e1+e2;
    sc[9]=e0/es; sc[10]=e1/es; sc[11]=e2/es;
    sc[12] = 1.f + softplusf_(ob[139]);
  }
  if (t >= 256 && t < 384) {
    int i = t - 256;
    kvec[i] = (i < 64) ? ob[i] : ob[70 + (i-64)];
  }
  if (t >= 384 && t < 512) {
    int i = t - 384;
    params[b*PSTRIDE + i] = (i < 64) ? sigmoidf_(ob[140+i]) : ob[204 + (i-64)];
  }
  __syncthreads();

  // --- P3: cosine sim, 4 lanes/row x 64B/lane, 8 passes, 2-deep pipeline
  {
    int rr = t >> 2, sub = t & 3;           // rr 0..255, sub 0..3
    float4 kr[4], kw[4];
    #pragma unroll
    for (int j=0;j<4;++j){
      kr[j] = ((const float4*)kvec)[4*sub + j];
      kw[j] = ((const float4*)(kvec+64))[4*sub + j];
    }
    float cr = sc[0]*sc[6];
    float cw = sc[7]*sc[13];
    const float4* m4 = (const float4*)mem + ((size_t)b*Nn)*16;
    float4 cur[4];
    #pragma unroll
    for (int j=0;j<4;++j) cur[j] = m4[(size_t)rr*16 + 4*sub + j];
    for (int p = 0; p < 8; ++p) {
      float4 cc[4];
      #pragma unroll
      for (int j=0;j<4;++j) cc[j] = cur[j];
      if (p < 7) {
        int nn = (p+1)*256 + rr;
        #pragma unroll
        for (int j=0;j<4;++j) cur[j] = m4[(size_t)nn*16 + 4*sub + j];
      }
      float ss=0.f, pr=0.f, pw=0.f;
      #pragma unroll
      for (int j=0;j<4;++j){
        ss += cc[j].x*cc[j].x + cc[j].y*cc[j].y + cc[j].z*cc[j].z + cc[j].w*cc[j].w;
        pr += cc[j].x*kr[j].x + cc[j].y*kr[j].y + cc[j].z*kr[j].z + cc[j].w*kr[j].w;
        pw += cc[j].x*kw[j].x + cc[j].y*kw[j].y + cc[j].z*kw[j].z + cc[j].w*kw[j].w;
      }
      #pragma unroll
      for (int off=2; off; off>>=1) {
        ss += __shfl_xor(ss, off);
        pr += __shfl_xor(pr, off);
        pw += __shfl_xor(pw, off);
      }
      if (sub == 0) {
        int n = p*256 + rr;
        float inv_nm = 1.f/(sqrtf(ss)+1e-8f);
        sim[0][n] = cr * pr * inv_nm;
        sim[1][n] = cw * pw * inv_nm;
      }
    }
  }
  __syncthreads();

  // --- P4: dual softmax/interp/shift/sharpen (half-block per head)
  {
    const float* S = sc + which*7;
    float g = S[1], s0 = S[2], s1 = S[3], s2 = S[4], gamma = S[5];
    float4 v4 = *(const float4*)&sim[which][tt*4];
    float v[4] = {v4.x, v4.y, v4.z, v4.w};
    float lmax = fmaxf(fmaxf(v[0],v[1]), fmaxf(v[2],v[3]));
    float mx = hreduce(lmax, red, t, true);
    float e[4]; float ps = 0.f;
    #pragma unroll
    for (int i=0;i<4;++i){ e[i] = expf(v[i]-mx); ps += e[i]; }
    float denom = hreduce(ps, red, t, false);
    float inv = 1.f/denom;
    float pv[4] = {p4.x, p4.y, p4.z, p4.w};
    float* wg = sim[which];
    #pragma unroll
    for (int i=0;i<4;++i){
      float wc = e[i]*inv;
      wg[tt*4+i] = g*wc + (1.f-g)*pv[i];
    }
    __syncthreads();
    float wp[4]; float psum = 0.f;
    #pragma unroll
    for (int i=0;i<4;++i){
      int n = tt*4+i;
      float wsv = s0*wg[(n+Nn-1)&(Nn-1)] + s1*wg[n] + s2*wg[(n+1)&(Nn-1)];
      wp[i] = powf(wsv, gamma);
      psum += wp[i];
    }
    float tot = hreduce(psum, red, t, false);
    float invt = 1.f/(tot + 1e-8f);
    float4 o4 = {wp[0]*invt, wp[1]*invt, wp[2]*invt, wp[3]*invt};
    ((float4*)outw)[tt] = o4;
  }
}

// ---------------- Kernel 3: per-batch memory update + read_vec + out GEMV
__global__ __launch_bounds__(1024) void k_mo(
    const float* __restrict__ mem, const float* __restrict__ params,
    const float* __restrict__ w_read, const float* __restrict__ w_write,
    const float* __restrict__ h_new,
    const float* __restrict__ W_o, const float* __restrict__ b_o,
    float* __restrict__ mem_new, float* __restrict__ read_vec, float* __restrict__ out)
{
  __shared__ __align__(16) float4 part[16][16];   // [wave][chunk]
  __shared__ __align__(16) float vbuf[576];
  int b = blockIdx.x, t = threadIdx.x;
  const float* P = params + b*PSTRIDE;
  int chunk = t & 15;
  int rr = t >> 4;                 // 0..63
  int wave = t >> 6, lane = t & 63;
  // erase/add read direct (same 16B broadcast within 16-lane group; L2-hot)
  float4 e4 = ((const float4*)P)[chunk];
  float4 a4 = ((const float4*)(P+64))[chunk];
  if (t < CSd) vbuf[t] = h_new[b*CSd + t];

  // --- P1: stream memory rows in pairs (128 rows in flight, 16 passes)
  const float4* m4 = (const float4*)mem     + ((size_t)b*Nn)*16;
  float4*       o4p = (float4*)mem_new      + ((size_t)b*Nn)*16;
  const float*  wwb = w_write + b*Nn;
  const float*  wrb = w_read  + b*Nn;
  float4 acc = {0.f,0.f,0.f,0.f};
  #pragma unroll 2
  for (int p = 0; p < 16; ++p) {
    int n1 = p*128 + rr, n2 = n1 + 64;
    float4 v1 = m4[(size_t)n1*16 + chunk];
    float4 v2 = m4[(size_t)n2*16 + chunk];
    float ww1 = wwb[n1], wr1 = wrb[n1];
    float ww2 = wwb[n2], wr2 = wrb[n2];
    float4 o1, o2;
    o1.x = v1.x*(1.f-ww1*e4.x) + ww1*a4.x;
    o1.y = v1.y*(1.f-ww1*e4.y) + ww1*a4.y;
    o1.z = v1.z*(1.f-ww1*e4.z) + ww1*a4.z;
    o1.w = v1.w*(1.f-ww1*e4.w) + ww1*a4.w;
    o2.x = v2.x*(1.f-ww2*e4.x) + ww2*a4.x;
    o2.y = v2.y*(1.f-ww2*e4.y) + ww2*a4.y;
    o2.z = v2.z*(1.f-ww2*e4.z) + ww2*a4.z;
    o2.w = v2.w*(1.f-ww2*e4.w) + ww2*a4.w;
    o4p[(size_t)n1*16 + chunk] = o1;
    o4p[(size_t)n2*16 + chunk] = o2;
    acc.x += wr1*v1.x + wr2*v2.x;
    acc.y += wr1*v1.y + wr2*v2.y;
    acc.z += wr1*v1.z + wr2*v2.z;
    acc.w += wr1*v1.w + wr2*v2.w;
  }
  #pragma unroll
  for (int off = 16; off <= 32; off <<= 1) {
    acc.x += __shfl_xor(acc.x, off);
    acc.y += __shfl_xor(acc.y, off);
    acc.z += __shfl_xor(acc.z, off);
    acc.w += __shfl_xor(acc.w, off);
  }
  if (lane < 16) part[wave][chunk] = acc;
  __syncthreads();

  // --- P2: finish read_vec reduction
  if (t < 16) {
    float4 s = part[0][t];
    #pragma unroll
    for (int w=1; w<16; ++w){ float4 q = part[w][t]; s.x+=q.x; s.y+=q.y; s.z+=q.z; s.w+=q.w; }
    *(float4*)&vbuf[512 + t*4] = s;
    *(float4*)&read_vec[b*64 + t*4] = s;
  }
  __syncthreads();

  // --- P3: out GEMV (16 waves x 16 cols)
  float vb[9];
  #pragma unroll
  for (int i = 0; i < 9; ++i) vb[i] = vbuf[i*64 + lane];
  for (int jj = 0; jj < 16; ++jj) {
    int cc = wave*16 + jj;
    const float* w = W_o + cc*576;
    float s = 0.f;
    #pragma unroll
    for (int i = 0; i < 9; ++i) s += w[i*64 + lane] * vb[i];
    #pragma unroll
    for (int off = 32; off; off >>= 1) s += __shfl_xor(s, off);
    if (lane == 0) out[b*OUTd + cc] = s + b_o[cc];
  }
}

extern "C" void kernel_launch(void* const* d_in, const int* in_sizes, int n_in,
                              void* d_out, int out_size, void* d_ws, size_t ws_size,
                              hipStream_t stream)
{
  const float* x         = (const float*)d_in[0];
  const float* memory    = (const float*)d_in[1];
  const float* h         = (const float*)d_in[2];
  const float* c         = (const float*)d_in[3];
  const float* read_w    = (const float*)d_in[4];
  const float* write_w   = (const float*)d_in[5];
  const float* prev_read = (const float*)d_in[6];
  const float* W_ih      = (const float*)d_in[7];
  const float* W_hh      = (const float*)d_in[8];
  const float* b_ih      = (const float*)d_in[9];
  const float* b_hh      = (const float*)d_in[10];
  const float* W_r       = (const float*)d_in[11];
  const float* b_r       = (const float*)d_in[12];
  const float* W_w       = (const float*)d_in[13];
  const float* b_w       = (const float*)d_in[14];
  const float* W_o       = (const float*)d_in[15];
  const float* b_o       = (const float*)d_in[16];

  float* out      = (float*)d_out;
  float* mem_new  = out + 256*256;
  float* h_new    = mem_new + (size_t)256*2048*64;
  float* c_new    = h_new + 256*512;
  float* w_read   = c_new + 256*512;
  float* w_write  = w_read + 256*2048;
  float* read_vec = w_write + 256*2048;

  float* ws       = (float*)d_ws;
  float* params   = ws;                      // 256*PSTRIDE floats
  float* partials = params + 256*PSTRIDE;    // ZSPL * GSZ floats (4 MB)

  k_gates<<<dim3(32,4,ZSPL), 256, 0, stream>>>(x, prev_read, h, W_ih, W_hh, partials);
  k_fused<<<256, 1024, 0, stream>>>(partials, c, b_ih, b_hh, W_r, b_r, W_w, b_w,
                                    memory, read_w, write_w,
                                    h_new, c_new, w_read, w_write, params);
  k_mo   <<<256, 1024, 0, stream>>>(memory, params, w_read, w_write, h_new,
                                    W_o, b_o, mem_new, read_vec, out);
}